// Round 1
// baseline (1174.954 us; speedup 1.0000x reference)
//
#include <hip/hip_runtime.h>

#define Bb   16
#define FIN  64
#define FOUT 128
#define NN   2048
#define KK   20
#define K2   24   // capture-list size (top-24 in fp32, refined to top-20 in fp64)

typedef unsigned long long u64;

// ---------------------------------------------------------------- sq norms
__global__ __launch_bounds__(256) void k_sqnorm(const float* __restrict__ x,
                                                float* __restrict__ sq) {
  int idx = blockIdx.x * 256 + threadIdx.x;       // over Bb*NN
  int b = idx >> 11, n = idx & (NN - 1);
  const float* xb = x + (size_t)b * FIN * NN + n;
  float s = 0.f;
#pragma unroll
  for (int f = 0; f < FIN; ++f) { float v = xb[(size_t)f * NN]; s += v * v; }
  sq[idx] = s;
}

// ---------------------------------------------------------------- P/Q GEMM
// P[b,o,n] = sum_f (W[o,f]-W[o,64+f]) x[b,f,n] + bias[o]
// Q[b,o,n] = sum_f  W[o,64+f]         x[b,f,n]
__global__ __launch_bounds__(256) void k_pq(const float* __restrict__ x,
                                            const float* __restrict__ W,
                                            const float* __restrict__ bias,
                                            float* __restrict__ P,
                                            float* __restrict__ Q) {
  __shared__ float Ws[64][68];
  __shared__ float xs[64][68];
  int nt = blockIdx.x, ot = blockIdx.y, b = blockIdx.z;
  int tid = threadIdx.x;
  for (int i = tid; i < 64 * 64; i += 256) {
    int f = i & 63, r = i >> 6;
    int R = ot * 64 + r;
    float w;
    if (R < FOUT) w = W[R * 2 * FIN + f] - W[R * 2 * FIN + FIN + f];
    else          w = W[(R - FOUT) * 2 * FIN + FIN + f];
    Ws[r][f] = w;
  }
  const float* xb = x + (size_t)b * FIN * NN + nt * 64;
  for (int i = tid; i < 64 * 64; i += 256) {
    int nn = i & 63, f = i >> 6;
    xs[nn][f] = xb[(size_t)f * NN + nn];
  }
  __syncthreads();
  int tx = tid & 15, ty = tid >> 4;
  int r0 = ty * 4;
  float acc[4][4] = {};
#pragma unroll
  for (int f = 0; f < 64; f += 4) {
    float4 a[4], c[4];
#pragma unroll
    for (int i = 0; i < 4; ++i) a[i] = *(const float4*)&Ws[r0 + i][f];
#pragma unroll
    for (int j = 0; j < 4; ++j) c[j] = *(const float4*)&xs[tx + 16 * j][f];
#pragma unroll
    for (int i = 0; i < 4; ++i)
#pragma unroll
      for (int j = 0; j < 4; ++j)
        acc[i][j] += a[i].x * c[j].x + a[i].y * c[j].y + a[i].z * c[j].z + a[i].w * c[j].w;
  }
#pragma unroll
  for (int i = 0; i < 4; ++i) {
    int R = ot * 64 + r0 + i;
    if (R < FOUT) {
      float bv = bias[R];
#pragma unroll
      for (int j = 0; j < 4; ++j)
        P[((size_t)b * FOUT + R) * NN + nt * 64 + tx + 16 * j] = acc[i][j] + bv;
    } else {
#pragma unroll
      for (int j = 0; j < 4; ++j)
        Q[((size_t)b * FOUT + (R - FOUT)) * NN + nt * 64 + tx + 16 * j] = acc[i][j];
    }
  }
}

// ---------------------------------------------------------------- kNN
// fp32 tiled distance GEMM + streaming per-row top-K2 capture, fp64 refine.
__global__ __launch_bounds__(256) void k_knn(const float* __restrict__ x,
                                             const float* __restrict__ sq,
                                             int* __restrict__ knn) {
  __shared__ float xi[64][68];
  __shared__ float xj[64][68];
  __shared__ float dt[64][68];
  __shared__ float sqi_s[64];
  __shared__ float sqj_s[64];
  __shared__ float topd[64][K2];
  __shared__ int   topi[64][K2];

  int it = blockIdx.x, b = blockIdx.y;
  int ibase = it * 64;
  int tid = threadIdx.x;
  int lane = tid & 63, w = tid >> 6;
  const float* xb = x + (size_t)b * FIN * NN;

  for (int i = tid; i < 64 * 64; i += 256) {
    int ii = i & 63, f = i >> 6;
    xi[ii][f] = xb[(size_t)f * NN + ibase + ii];
  }
  if (tid < 64) sqi_s[tid] = sq[b * NN + ibase + tid];
  for (int i = tid; i < 64 * K2; i += 256) {
    topd[i / K2][i % K2] = 3.4e38f;
    topi[i / K2][i % K2] = -1;
  }

  int tx = lane & 15, tyw = lane >> 4;
  int ty = w * 4 + tyw;      // 0..15; wave w owns local rows [16w,16w+16)
  int i0 = ty * 4;

  for (int jt = 0; jt < NN / 64; ++jt) {
    __syncthreads();
    int jbase = jt * 64;
    for (int i = tid; i < 64 * 64; i += 256) {
      int jj = i & 63, f = i >> 6;
      xj[jj][f] = xb[(size_t)f * NN + jbase + jj];
    }
    if (tid < 64) sqj_s[tid] = sq[b * NN + jbase + tid];
    __syncthreads();

    float acc[4][4] = {};
#pragma unroll
    for (int f = 0; f < 64; f += 4) {
      float4 a[4], c[4];
#pragma unroll
      for (int i = 0; i < 4; ++i) a[i] = *(const float4*)&xi[i0 + i][f];
#pragma unroll
      for (int j = 0; j < 4; ++j) c[j] = *(const float4*)&xj[tx + 16 * j][f];
#pragma unroll
      for (int i = 0; i < 4; ++i)
#pragma unroll
        for (int j = 0; j < 4; ++j)
          acc[i][j] += a[i].x * c[j].x + a[i].y * c[j].y + a[i].z * c[j].z + a[i].w * c[j].w;
    }
#pragma unroll
    for (int i = 0; i < 4; ++i) {
      float si = sqi_s[i0 + i];
#pragma unroll
      for (int j = 0; j < 4; ++j) {
        int jl = tx + 16 * j;
        dt[i0 + i][jl] = (-2.f * acc[i][j] + si) + sqj_s[jl];
      }
    }
    // per-row streaming insert into sorted top-K2 (rows owned by this wave)
    for (int r = 0; r < 16; ++r) {
      int row = w * 16 + r;
      int iglob = ibase + row;
      float thr = topd[row][K2 - 1];
      float d = dt[row][lane];
      int j = jbase + lane;
      u64 m = __ballot(d < thr && j != iglob);
      if (m) {
        float ed = (lane < K2) ? topd[row][lane] : 3.4e38f;
        int   ei = (lane < K2) ? topi[row][lane] : -1;
        while (m) {
          int src = __ffsll(m) - 1;
          m &= m - 1;
          float dl = __shfl(d, src);
          int   jl = __shfl(j, src);
          u64 less = __ballot(ed <= dl && lane < K2);
          int pos = __popcll(less);
          if (pos < K2) {
            float sd = __shfl_up(ed, 1);
            int   si2 = __shfl_up(ei, 1);
            if (lane >= pos && lane < K2) {
              ed = (lane == pos) ? dl : sd;
              ei = (lane == pos) ? jl : si2;
            }
          }
        }
        if (lane < K2) { topd[row][lane] = ed; topi[row][lane] = ei; }
      }
    }
  }

  // fp64 refine: exact ranking of the <=K2 captured candidates, emit top-20.
  for (int r = 0; r < 16; ++r) {
    int row = w * 16 + r;
    int iglob = ibase + row;
    int j = (lane < K2) ? topi[row][lane] : -1;
    double dd = 1e300;
    if (j >= 0) {
      double dot = 0.0, sj = 0.0, si = 0.0;
      for (int f = 0; f < FIN; ++f) {
        double xiv = (double)xi[row][f];
        double xjv = (double)xb[(size_t)f * NN + j];
        dot += xiv * xjv;
        si += xiv * xiv;
        sj += xjv * xjv;
      }
      dd = si + sj - 2.0 * dot;
    }
    int jv = j;
    for (int k = 0; k < KK; ++k) {
      double bd = dd; int bj = jv; int bl = lane;
#pragma unroll
      for (int off = 32; off; off >>= 1) {
        double od = __shfl_xor(bd, off);
        int    oj = __shfl_xor(bj, off);
        int    ol = __shfl_xor(bl, off);
        if (od < bd || (od == bd && ((unsigned)oj < (unsigned)bj))) { bd = od; bj = oj; bl = ol; }
      }
      if (lane == 0) knn[((size_t)b * NN + iglob) * KK + k] = bj;
      if (lane == bl) dd = 1e300;
    }
  }
}

// ---------------------------------------------------------------- stats + per-(b,o,n) max/min
__global__ __launch_bounds__(256) void k_stats(const float* __restrict__ P,
                                               const float* __restrict__ Q,
                                               const int* __restrict__ knn,
                                               float* __restrict__ mx,
                                               float* __restrict__ mn,
                                               double* __restrict__ sums) {
  __shared__ float Qs[2][NN];
  __shared__ int   ks[256][21];   // +1 pad breaks stride-20 bank conflicts
  int nt = blockIdx.x, og = blockIdx.y, b = blockIdx.z;
  int tid = threadIdx.x;
  int nbase = nt * 256;
  for (int i = tid; i < 2 * NN; i += 256) {
    int ol = i >> 11, jj = i & (NN - 1);
    Qs[ol][jj] = Q[((size_t)b * FOUT + og * 2 + ol) * NN + jj];
  }
  for (int i = tid; i < 256 * KK; i += 256) {
    int nn = i / KK, k = i % KK;
    ks[nn][k] = knn[((size_t)b * NN + nbase + nn) * KK + k];
  }
  __syncthreads();
  int ol = tid >> 7, ln = tid & 127;
  int o = og * 2 + ol;
  float s1 = 0.f, s2 = 0.f;
#pragma unroll
  for (int s = 0; s < 2; ++s) {
    int nn = ln + 128 * s;
    int n = nbase + nn;
    float p = P[((size_t)b * FOUT + o) * NN + n];
    float vmx = -3.4e38f, vmn = 3.4e38f;
#pragma unroll
    for (int k = 0; k < KK; ++k) {
      float y = p + Qs[ol][ks[nn][k]];
      s1 += y; s2 += y * y;
      vmx = fmaxf(vmx, y); vmn = fminf(vmn, y);
    }
    mx[((size_t)b * FOUT + o) * NN + n] = vmx;
    mn[((size_t)b * FOUT + o) * NN + n] = vmn;
  }
#pragma unroll
  for (int off = 32; off; off >>= 1) { s1 += __shfl_xor(s1, off); s2 += __shfl_xor(s2, off); }
  if ((tid & 63) == 0) {
    atomicAdd(&sums[o], (double)s1);
    atomicAdd(&sums[FOUT + o], (double)s2);
  }
}

// ---------------------------------------------------------------- finalize BN params
__global__ void k_finalize(const double* __restrict__ sums, const float* __restrict__ gamma,
                           const float* __restrict__ beta, float* __restrict__ ss) {
  int o = threadIdx.x;
  if (o < FOUT) {
    double cnt = (double)Bb * NN * KK;
    double mean = sums[o] / cnt;
    double var = sums[FOUT + o] / cnt - mean * mean;
    double inv = 1.0 / sqrt(var + 1e-5);
    double scale = (double)gamma[o] * inv;
    ss[o] = (float)scale;
    ss[FOUT + o] = (float)((double)beta[o] - mean * scale);
  }
}

// ---------------------------------------------------------------- epilogue
__global__ __launch_bounds__(256) void k_out(const float* __restrict__ mx,
                                             const float* __restrict__ mn,
                                             const float* __restrict__ ss,
                                             float* __restrict__ out) {
  int idx = blockIdx.x * 256 + threadIdx.x;   // Bb*FOUT*NN
  int o = (idx >> 11) & (FOUT - 1);
  float sc = ss[o], sh = ss[FOUT + o];
  float v = (sc >= 0.f) ? mx[idx] : mn[idx];
  out[idx] = fmaxf(sc * v + sh, 0.f);
}

// ---------------------------------------------------------------- launch
extern "C" void kernel_launch(void* const* d_in, const int* in_sizes, int n_in,
                              void* d_out, int out_size, void* d_ws, size_t ws_size,
                              hipStream_t stream) {
  const float* x     = (const float*)d_in[0];
  const float* W     = (const float*)d_in[1];
  const float* bias  = (const float*)d_in[2];
  const float* gamma = (const float*)d_in[3];
  const float* beta  = (const float*)d_in[4];
  float* out = (float*)d_out;

  char* ws = (char*)d_ws;
  const size_t PN = (size_t)Bb * FOUT * NN;          // 4,194,304
  float* P  = (float*)ws;  ws += PN * 4;
  float* Q  = (float*)ws;  ws += PN * 4;
  float* mx = (float*)ws;  ws += PN * 4;
  float* mn = (float*)ws;  ws += PN * 4;
  float* sq = (float*)ws;  ws += (size_t)Bb * NN * 4;
  int*   knn = (int*)ws;   ws += (size_t)Bb * NN * KK * 4;
  double* sums = (double*)ws; ws += 2 * FOUT * 8;
  float* ss = (float*)ws;  ws += 2 * FOUT * 4;

  hipMemsetAsync(sums, 0, 2 * FOUT * 8, stream);

  k_sqnorm<<<Bb * NN / 256, 256, 0, stream>>>(x, sq);
  k_pq<<<dim3(32, 4, Bb), 256, 0, stream>>>(x, W, bias, P, Q);
  k_knn<<<dim3(NN / 64, Bb), 256, 0, stream>>>(x, sq, knn);
  k_stats<<<dim3(8, 64, Bb), 256, 0, stream>>>(P, Q, knn, mx, mn, sums);
  k_finalize<<<1, 128, 0, stream>>>(sums, gamma, beta, ss);
  k_out<<<(int)(PN / 256), 256, 0, stream>>>(mx, mn, ss, out);
}

// Round 2
// 630.682 us; speedup vs baseline: 1.8630x; 1.8630x over previous
//
#include <hip/hip_runtime.h>
#include <hip/hip_bf16.h>

#define Bb   16
#define FIN  64
#define FOUT 128
#define NN   2048
#define KK   20
#define K2   24   // capture top-24 (approx), refine to top-20 (exact fp64)

typedef unsigned long long u64;
typedef __attribute__((ext_vector_type(8))) __bf16 bf16x8;
typedef __attribute__((ext_vector_type(4))) float  f32x4;

static __device__ __forceinline__ unsigned short f2bf(float f) {
  unsigned u = __float_as_uint(f);
  unsigned r = (u + 0x7fff + ((u >> 16) & 1)) >> 16;   // RNE
  return (unsigned short)r;
}
static __device__ __forceinline__ float bf2f(unsigned short b) {
  return __uint_as_float(((unsigned)b) << 16);
}
static __device__ __forceinline__ void gll16(const void* g, void* l) {
  __builtin_amdgcn_global_load_lds(
      (const __attribute__((address_space(1))) unsigned int*)g,
      (__attribute__((address_space(3))) unsigned int*)l, 16, 0, 0);
}

// ---------------------------------------------------------------- prep:
// transpose x -> xt32[b][n][f] (fp32), bf16 hi/lo split packed in MFMA
// fragment order: xth/xtl element ((b*128+p)*2+ck)*512 + lane*8 + e, where
// point n = 16p + (lane&15), f = ck*32 + (lane>>4)*8 + e.  Also sq[b][n].
__global__ __launch_bounds__(256) void k_prep(const float* __restrict__ x,
                                              unsigned short* __restrict__ xth,
                                              unsigned short* __restrict__ xtl,
                                              float* __restrict__ xt32,
                                              float* __restrict__ sq) {
  __shared__ float ts[FIN][65];
  int nt = blockIdx.x, b = blockIdx.y;
  int nbase = nt * 64, tid = threadIdx.x;
  for (int i = tid; i < 64 * 64; i += 256) {
    int f = i >> 6, j = i & 63;
    ts[f][j] = x[((size_t)b * FIN + f) * NN + nbase + j];
  }
  __syncthreads();
  if (tid < 64) {
    float s = 0.f;
#pragma unroll
    for (int f = 0; f < FIN; ++f) { float v = ts[f][tid]; s += v * v; }
    sq[b * NN + nbase + tid] = s;
  }
  for (int u = tid; u < 512; u += 256) {
    int lane = u & 63, ck = (u >> 6) & 1, pg = u >> 7;
    int j = pg * 16 + (lane & 15);
    int kg = lane >> 4;
    int fbase = ck * 32 + kg * 8;
    float v[8]; unsigned short h[8], l[8];
#pragma unroll
    for (int e = 0; e < 8; ++e) {
      v[e] = ts[fbase + e][j];
      h[e] = f2bf(v[e]);
      l[e] = f2bf(v[e] - bf2f(h[e]));
    }
    size_t po = (((size_t)b * (NN / 16) + (nbase >> 4) + pg) * 2 + ck) * 512 + lane * 8;
    ushort4* dh = (ushort4*)(xth + po);
    dh[0] = make_ushort4(h[0], h[1], h[2], h[3]);
    dh[1] = make_ushort4(h[4], h[5], h[6], h[7]);
    ushort4* dl = (ushort4*)(xtl + po);
    dl[0] = make_ushort4(l[0], l[1], l[2], l[3]);
    dl[1] = make_ushort4(l[4], l[5], l[6], l[7]);
    float* d32 = xt32 + ((size_t)b * NN + nbase + j) * FIN + fbase;
    *(float4*)d32       = make_float4(v[0], v[1], v[2], v[3]);
    *(float4*)(d32 + 4) = make_float4(v[4], v[5], v[6], v[7]);
  }
}

// ---------------------------------------------------------------- P/Q GEMM
__global__ __launch_bounds__(256) void k_pq(const float* __restrict__ x,
                                            const float* __restrict__ W,
                                            const float* __restrict__ bias,
                                            float* __restrict__ P,
                                            float* __restrict__ Q) {
  __shared__ float Ws[64][68];
  __shared__ float xs[64][68];
  int nt = blockIdx.x, ot = blockIdx.y, b = blockIdx.z;
  int tid = threadIdx.x;
  for (int i = tid; i < 64 * 64; i += 256) {
    int f = i & 63, r = i >> 6;
    int R = ot * 64 + r;
    float w;
    if (R < FOUT) w = W[R * 2 * FIN + f] - W[R * 2 * FIN + FIN + f];
    else          w = W[(R - FOUT) * 2 * FIN + FIN + f];
    Ws[r][f] = w;
  }
  const float* xb = x + (size_t)b * FIN * NN + nt * 64;
  for (int i = tid; i < 64 * 64; i += 256) {
    int nn = i & 63, f = i >> 6;
    xs[nn][f] = xb[(size_t)f * NN + nn];
  }
  __syncthreads();
  int tx = tid & 15, ty = tid >> 4;
  int r0 = ty * 4;
  float acc[4][4] = {};
#pragma unroll
  for (int f = 0; f < 64; f += 4) {
    float4 a[4], c[4];
#pragma unroll
    for (int i = 0; i < 4; ++i) a[i] = *(const float4*)&Ws[r0 + i][f];
#pragma unroll
    for (int j = 0; j < 4; ++j) c[j] = *(const float4*)&xs[tx + 16 * j][f];
#pragma unroll
    for (int i = 0; i < 4; ++i)
#pragma unroll
      for (int j = 0; j < 4; ++j)
        acc[i][j] += a[i].x * c[j].x + a[i].y * c[j].y + a[i].z * c[j].z + a[i].w * c[j].w;
  }
#pragma unroll
  for (int i = 0; i < 4; ++i) {
    int R = ot * 64 + r0 + i;
    if (R < FOUT) {
      float bv = bias[R];
#pragma unroll
      for (int j = 0; j < 4; ++j)
        P[((size_t)b * FOUT + R) * NN + nt * 64 + tx + 16 * j] = acc[i][j] + bv;
    } else {
#pragma unroll
      for (int j = 0; j < 4; ++j)
        Q[((size_t)b * FOUT + (R - FOUT)) * NN + nt * 64 + tx + 16 * j] = acc[i][j];
    }
  }
}

// ---------------------------------------------------------------- kNN
// MFMA bf16 hi/lo distance GEMM + register top-K2 + exact fp64 refine.
__global__ __launch_bounds__(512) void k_knn(const unsigned short* __restrict__ xth,
                                             const unsigned short* __restrict__ xtl,
                                             const float* __restrict__ xt32,
                                             const float* __restrict__ sq,
                                             int* __restrict__ knn) {
  __shared__ unsigned short BjH[4096];   // 8 KB, frag-linear
  __shared__ unsigned short BjL[4096];   // 8 KB
  __shared__ float dt[64][68];           // 17.4 KB
  __shared__ float sqi_s[64], sqj_s[64];

  int it = blockIdx.x, b = blockIdx.y;
  int ibase = it * 64, tid = threadIdx.x;
  int lane = tid & 63, w = tid >> 6;     // 8 waves

  const unsigned short* xhB = xth + (size_t)b * (NN / 16) * 1024;
  const unsigned short* xlB = xtl + (size_t)b * (NN / 16) * 1024;

  // A fragments for this wave's MFMA tile-row (rows 16*tr..16*tr+16), in regs
  int tr = w >> 1;
  size_t pa = ((size_t)(ibase >> 4) + tr) * 1024;
  bf16x8 ah0 = *(const bf16x8*)(xhB + pa +       lane * 8);
  bf16x8 ah1 = *(const bf16x8*)(xhB + pa + 512 + lane * 8);
  bf16x8 al0 = *(const bf16x8*)(xlB + pa +       lane * 8);
  bf16x8 al1 = *(const bf16x8*)(xlB + pa + 512 + lane * 8);

  if (tid < 64) sqi_s[tid] = sq[b * NN + ibase + tid];

  float ed[8]; int ei[8];
#pragma unroll
  for (int r = 0; r < 8; ++r) { ed[r] = 3.4e38f; ei[r] = -1; }

  // stage tile 0
  gll16(xhB + 0 + tid * 8, BjH + tid * 8);
  gll16(xlB + 0 + tid * 8, BjL + tid * 8);
  if (tid < 64) sqj_s[tid] = sq[b * NN + tid];

  for (int jt = 0; jt < NN / 64; ++jt) {
    __syncthreads();                       // staged tile + sqj ready
    // ---- MFMA: 2 tiles (16x16) per wave, K=64 via 2 chunks x 3 terms
#pragma unroll
    for (int ti = 0; ti < 2; ++ti) {
      int tc = (w & 1) * 2 + ti;
      bf16x8 bh0 = *(const bf16x8*)(BjH + (tc * 2 + 0) * 512 + lane * 8);
      bf16x8 bh1 = *(const bf16x8*)(BjH + (tc * 2 + 1) * 512 + lane * 8);
      bf16x8 bl0 = *(const bf16x8*)(BjL + (tc * 2 + 0) * 512 + lane * 8);
      bf16x8 bl1 = *(const bf16x8*)(BjL + (tc * 2 + 1) * 512 + lane * 8);
      f32x4 acc = {0.f, 0.f, 0.f, 0.f};
      acc = __builtin_amdgcn_mfma_f32_16x16x32_bf16(ah0, bh0, acc, 0, 0, 0);
      acc = __builtin_amdgcn_mfma_f32_16x16x32_bf16(ah1, bh1, acc, 0, 0, 0);
      acc = __builtin_amdgcn_mfma_f32_16x16x32_bf16(ah0, bl0, acc, 0, 0, 0);
      acc = __builtin_amdgcn_mfma_f32_16x16x32_bf16(ah1, bl1, acc, 0, 0, 0);
      acc = __builtin_amdgcn_mfma_f32_16x16x32_bf16(al0, bh0, acc, 0, 0, 0);
      acc = __builtin_amdgcn_mfma_f32_16x16x32_bf16(al1, bh1, acc, 0, 0, 0);
      int jl = tc * 16 + (lane & 15);
      float sj = sqj_s[jl];
#pragma unroll
      for (int e = 0; e < 4; ++e) {
        int il = tr * 16 + (lane >> 4) * 4 + e;
        dt[il][jl] = sqi_s[il] + sj - 2.f * acc[e];
      }
    }
    __syncthreads();                       // dt ready, Bj free for overwrite
    int jbase = jt * 64;
    if (jt + 1 < NN / 64) {                // prefetch next tile under selection
      const unsigned short* sh = xhB + (size_t)(jt + 1) * 4096;
      const unsigned short* sl = xlB + (size_t)(jt + 1) * 4096;
      gll16(sh + tid * 8, BjH + tid * 8);
      gll16(sl + tid * 8, BjL + tid * 8);
      if (tid < 64) sqj_s[tid] = sq[b * NN + (jt + 1) * 64 + tid];
    }
    // ---- selection: wave w owns rows 8w..8w+8
    if (jt == 0) {
#pragma unroll
      for (int r = 0; r < 8; ++r) {
        int row = w * 8 + r, iglob = ibase + row;
        float d = dt[row][lane]; int j = lane;
        if (j == iglob) d = 3.4e38f;
#pragma unroll
        for (int size = 2; size <= 64; size <<= 1) {
#pragma unroll
          for (int stride = size >> 1; stride; stride >>= 1) {
            float od = __shfl_xor(d, stride);
            int   oj = __shfl_xor(j, stride);
            bool up = (lane & size) == 0;
            bool lower = (lane & stride) == 0;
            bool lt = (od < d) || (od == d && oj < j);
            bool take = (lower == up) ? lt : !lt;
            if (take) { d = od; j = oj; }
          }
        }
        if (lane < K2) { ed[r] = d; ei[r] = j; }
      }
    } else {
#pragma unroll
      for (int r = 0; r < 8; ++r) {
        int row = w * 8 + r, iglob = ibase + row;
        float thr = __shfl(ed[r], K2 - 1);
        float d = dt[row][lane]; int j = jbase + lane;
        u64 m = __ballot(d < thr && j != iglob);
        while (m) {
          int src = __ffsll(m) - 1;
          m &= m - 1;
          float dl = __shfl(d, src);
          int   jl = __shfl(j, src);
          u64 less = __ballot(ed[r] <= dl);
          int pos = __popcll(less);
          if (pos < K2) {
            float sd = __shfl_up(ed[r], 1);
            int   si = __shfl_up(ei[r], 1);
            if (lane >= pos && lane < K2) {
              ed[r] = (lane == pos) ? dl : sd;
              ei[r] = (lane == pos) ? jl : si;
            }
          }
        }
      }
    }
  }

  // ---- exact fp64 refine of the K2 candidates, emit top-20
  const float* x32B = xt32 + (size_t)b * NN * FIN;
#pragma unroll
  for (int r = 0; r < 8; ++r) {
    int row = w * 8 + r, iglob = ibase + row;
    int j = (lane < K2) ? ei[r] : -1;
    double dd = 1e300;
    if (j >= 0) {
      const float4* xi4 = (const float4*)(x32B + (size_t)iglob * FIN);
      const float4* xj4 = (const float4*)(x32B + (size_t)j * FIN);
      double s = 0.0;
#pragma unroll
      for (int q = 0; q < 16; ++q) {
        float4 a = xi4[q], c = xj4[q];
        double d0 = (double)a.x - (double)c.x;
        double d1 = (double)a.y - (double)c.y;
        double d2 = (double)a.z - (double)c.z;
        double d3 = (double)a.w - (double)c.w;
        s += d0 * d0 + d1 * d1 + d2 * d2 + d3 * d3;
      }
      dd = s;
    }
#pragma unroll
    for (int size = 2; size <= 64; size <<= 1) {
#pragma unroll
      for (int stride = size >> 1; stride; stride >>= 1) {
        double od = __shfl_xor(dd, stride);
        int    oj = __shfl_xor(j, stride);
        bool up = (lane & size) == 0;
        bool lower = (lane & stride) == 0;
        bool lt = (od < dd) || (od == dd && oj < j);
        bool take = (lower == up) ? lt : !lt;
        if (take) { dd = od; j = oj; }
      }
    }
    if (lane < KK) knn[((size_t)b * NN + iglob) * KK + lane] = j;
  }
}

// ---------------------------------------------------------------- stats
__global__ __launch_bounds__(256) void k_stats(const float* __restrict__ P,
                                               const float* __restrict__ Q,
                                               const int* __restrict__ knn,
                                               float* __restrict__ mx,
                                               float* __restrict__ mn,
                                               double* __restrict__ sums) {
  __shared__ float Qs[2][NN];
  __shared__ int   ks[256][21];
  int nt = blockIdx.x, og = blockIdx.y, b = blockIdx.z;
  int tid = threadIdx.x;
  int nbase = nt * 256;
  for (int i = tid; i < 2 * NN; i += 256) {
    int ol = i >> 11, jj = i & (NN - 1);
    Qs[ol][jj] = Q[((size_t)b * FOUT + og * 2 + ol) * NN + jj];
  }
  for (int i = tid; i < 256 * KK; i += 256) {
    int nn = i / KK, k = i % KK;
    ks[nn][k] = knn[((size_t)b * NN + nbase + nn) * KK + k];
  }
  __syncthreads();
  int ol = tid >> 7, ln = tid & 127;
  int o = og * 2 + ol;
  float s1 = 0.f, s2 = 0.f;
#pragma unroll
  for (int s = 0; s < 2; ++s) {
    int nn = ln + 128 * s;
    int n = nbase + nn;
    float p = P[((size_t)b * FOUT + o) * NN + n];
    float vmx = -3.4e38f, vmn = 3.4e38f;
#pragma unroll
    for (int k = 0; k < KK; ++k) {
      float y = p + Qs[ol][ks[nn][k]];
      s1 += y; s2 += y * y;
      vmx = fmaxf(vmx, y); vmn = fminf(vmn, y);
    }
    mx[((size_t)b * FOUT + o) * NN + n] = vmx;
    mn[((size_t)b * FOUT + o) * NN + n] = vmn;
  }
#pragma unroll
  for (int off = 32; off; off >>= 1) { s1 += __shfl_xor(s1, off); s2 += __shfl_xor(s2, off); }
  if ((tid & 63) == 0) {
    atomicAdd(&sums[o], (double)s1);
    atomicAdd(&sums[FOUT + o], (double)s2);
  }
}

// ---------------------------------------------------------------- finalize
__global__ void k_finalize(const double* __restrict__ sums, const float* __restrict__ gamma,
                           const float* __restrict__ beta, float* __restrict__ ss) {
  int o = threadIdx.x;
  if (o < FOUT) {
    double cnt = (double)Bb * NN * KK;
    double mean = sums[o] / cnt;
    double var = sums[FOUT + o] / cnt - mean * mean;
    double inv = 1.0 / sqrt(var + 1e-5);
    double scale = (double)gamma[o] * inv;
    ss[o] = (float)scale;
    ss[FOUT + o] = (float)((double)beta[o] - mean * scale);
  }
}

// ---------------------------------------------------------------- epilogue
__global__ __launch_bounds__(256) void k_out(const float* __restrict__ mx,
                                             const float* __restrict__ mn,
                                             const float* __restrict__ ss,
                                             float* __restrict__ out) {
  int idx = blockIdx.x * 256 + threadIdx.x;
  int o = (idx >> 11) & (FOUT - 1);
  float sc = ss[o], sh = ss[FOUT + o];
  float v = (sc >= 0.f) ? mx[idx] : mn[idx];
  out[idx] = fmaxf(sc * v + sh, 0.f);
}

// ---------------------------------------------------------------- launch
extern "C" void kernel_launch(void* const* d_in, const int* in_sizes, int n_in,
                              void* d_out, int out_size, void* d_ws, size_t ws_size,
                              hipStream_t stream) {
  const float* x     = (const float*)d_in[0];
  const float* W     = (const float*)d_in[1];
  const float* bias  = (const float*)d_in[2];
  const float* gamma = (const float*)d_in[3];
  const float* beta  = (const float*)d_in[4];
  float* out = (float*)d_out;

  char* ws = (char*)d_ws;
  const size_t PN = (size_t)Bb * FOUT * NN;          // 4,194,304
  float* P  = (float*)ws;  ws += PN * 4;
  float* Q  = (float*)ws;  ws += PN * 4;
  float* mx = (float*)ws;  ws += PN * 4;             // 16 MB, aliased with xt*
  float* mn = (float*)ws;  ws += PN * 4;
  float* sq = (float*)ws;  ws += (size_t)Bb * NN * 4;
  int*   knn = (int*)ws;   ws += (size_t)Bb * NN * KK * 4;
  double* sums = (double*)ws; ws += 2 * FOUT * 8;
  float* ss = (float*)ws;  ws += 2 * FOUT * 4;

  // xth/xtl/xt32 alias the mx buffer (4+4+8 MB = 16 MB); k_stats overwrites
  // mx only after k_knn has finished reading them (stream-ordered).
  unsigned short* xth = (unsigned short*)mx;
  unsigned short* xtl = xth + (size_t)Bb * NN * FIN;
  float* xt32 = (float*)(xtl + (size_t)Bb * NN * FIN);

  hipMemsetAsync(sums, 0, 2 * FOUT * 8, stream);

  k_prep<<<dim3(NN / 64, Bb), 256, 0, stream>>>(x, xth, xtl, xt32, sq);
  k_pq<<<dim3(32, 4, Bb), 256, 0, stream>>>(x, W, bias, P, Q);
  k_knn<<<dim3(NN / 64, Bb), 512, 0, stream>>>(xth, xtl, xt32, sq, knn);
  k_stats<<<dim3(8, 64, Bb), 256, 0, stream>>>(P, Q, knn, mx, mn, sums);
  k_finalize<<<1, 128, 0, stream>>>(sums, gamma, beta, ss);
  k_out<<<(int)(PN / 256), 256, 0, stream>>>(mx, mn, ss, out);
}

// Round 3
// 537.834 us; speedup vs baseline: 2.1846x; 1.1726x over previous
//
#include <hip/hip_runtime.h>
#include <hip/hip_bf16.h>

#define Bb   16
#define FIN  64
#define FOUT 128
#define NN   2048
#define KK   20
#define K2   24   // capture top-24 (approx), refine to top-20 (exact fp64)

typedef unsigned long long u64;
typedef __attribute__((ext_vector_type(8))) __bf16 bf16x8;
typedef __attribute__((ext_vector_type(4))) float  f32x4;

static __device__ __forceinline__ unsigned short f2bf(float f) {
  unsigned u = __float_as_uint(f);
  unsigned r = (u + 0x7fff + ((u >> 16) & 1)) >> 16;   // RNE
  return (unsigned short)r;
}
static __device__ __forceinline__ float bf2f(unsigned short b) {
  return __uint_as_float(((unsigned)b) << 16);
}
static __device__ __forceinline__ void gll16(const void* g, void* l) {
  __builtin_amdgcn_global_load_lds(
      (const __attribute__((address_space(1))) unsigned int*)g,
      (__attribute__((address_space(3))) unsigned int*)l, 16, 0, 0);
}

// ---------------------------------------------------------------- prep:
// transpose x -> xt32[b][n][f] (fp32), bf16 hi/lo split packed in MFMA
// fragment order: xth/xtl element ((b*128+p)*2+ck)*512 + lane*8 + e, where
// point n = 16p + (lane&15), f = ck*32 + (lane>>4)*8 + e.  Also sq[b][n].
__global__ __launch_bounds__(256) void k_prep(const float* __restrict__ x,
                                              unsigned short* __restrict__ xth,
                                              unsigned short* __restrict__ xtl,
                                              float* __restrict__ xt32,
                                              float* __restrict__ sq) {
  __shared__ float ts[FIN][65];
  int nt = blockIdx.x, b = blockIdx.y;
  int nbase = nt * 64, tid = threadIdx.x;
  for (int i = tid; i < 64 * 64; i += 256) {
    int f = i >> 6, j = i & 63;
    ts[f][j] = x[((size_t)b * FIN + f) * NN + nbase + j];
  }
  __syncthreads();
  if (tid < 64) {
    float s = 0.f;
#pragma unroll
    for (int f = 0; f < FIN; ++f) { float v = ts[f][tid]; s += v * v; }
    sq[b * NN + nbase + tid] = s;
  }
  for (int u = tid; u < 512; u += 256) {
    int lane = u & 63, ck = (u >> 6) & 1, pg = u >> 7;
    int j = pg * 16 + (lane & 15);
    int kg = lane >> 4;
    int fbase = ck * 32 + kg * 8;
    float v[8]; unsigned short h[8], l[8];
#pragma unroll
    for (int e = 0; e < 8; ++e) {
      v[e] = ts[fbase + e][j];
      h[e] = f2bf(v[e]);
      l[e] = f2bf(v[e] - bf2f(h[e]));
    }
    size_t po = (((size_t)b * (NN / 16) + (nbase >> 4) + pg) * 2 + ck) * 512 + lane * 8;
    ushort4* dh = (ushort4*)(xth + po);
    dh[0] = make_ushort4(h[0], h[1], h[2], h[3]);
    dh[1] = make_ushort4(h[4], h[5], h[6], h[7]);
    ushort4* dl = (ushort4*)(xtl + po);
    dl[0] = make_ushort4(l[0], l[1], l[2], l[3]);
    dl[1] = make_ushort4(l[4], l[5], l[6], l[7]);
    float* d32 = xt32 + ((size_t)b * NN + nbase + j) * FIN + fbase;
    *(float4*)d32       = make_float4(v[0], v[1], v[2], v[3]);
    *(float4*)(d32 + 4) = make_float4(v[4], v[5], v[6], v[7]);
  }
}

// ---------------------------------------------------------------- P/Q GEMM
__global__ __launch_bounds__(256) void k_pq(const float* __restrict__ x,
                                            const float* __restrict__ W,
                                            const float* __restrict__ bias,
                                            float* __restrict__ P,
                                            float* __restrict__ Q) {
  __shared__ float Ws[64][68];
  __shared__ float xs[64][68];
  int nt = blockIdx.x, ot = blockIdx.y, b = blockIdx.z;
  int tid = threadIdx.x;
  for (int i = tid; i < 64 * 64; i += 256) {
    int f = i & 63, r = i >> 6;
    int R = ot * 64 + r;
    float w;
    if (R < FOUT) w = W[R * 2 * FIN + f] - W[R * 2 * FIN + FIN + f];
    else          w = W[(R - FOUT) * 2 * FIN + FIN + f];
    Ws[r][f] = w;
  }
  const float* xb = x + (size_t)b * FIN * NN + nt * 64;
  for (int i = tid; i < 64 * 64; i += 256) {
    int nn = i & 63, f = i >> 6;
    xs[nn][f] = xb[(size_t)f * NN + nn];
  }
  __syncthreads();
  int tx = tid & 15, ty = tid >> 4;
  int r0 = ty * 4;
  float acc[4][4] = {};
#pragma unroll
  for (int f = 0; f < 64; f += 4) {
    float4 a[4], c[4];
#pragma unroll
    for (int i = 0; i < 4; ++i) a[i] = *(const float4*)&Ws[r0 + i][f];
#pragma unroll
    for (int j = 0; j < 4; ++j) c[j] = *(const float4*)&xs[tx + 16 * j][f];
#pragma unroll
    for (int i = 0; i < 4; ++i)
#pragma unroll
      for (int j = 0; j < 4; ++j)
        acc[i][j] += a[i].x * c[j].x + a[i].y * c[j].y + a[i].z * c[j].z + a[i].w * c[j].w;
  }
#pragma unroll
  for (int i = 0; i < 4; ++i) {
    int R = ot * 64 + r0 + i;
    if (R < FOUT) {
      float bv = bias[R];
#pragma unroll
      for (int j = 0; j < 4; ++j)
        P[((size_t)b * FOUT + R) * NN + nt * 64 + tx + 16 * j] = acc[i][j] + bv;
    } else {
#pragma unroll
      for (int j = 0; j < 4; ++j)
        Q[((size_t)b * FOUT + (R - FOUT)) * NN + nt * 64 + tx + 16 * j] = acc[i][j];
    }
  }
}

// ---------------------------------------------------------------- kNN
// 32-row blocks, 8 waves: 1 MFMA tile/wave/jt, 4 selection rows/wave.
__global__ __launch_bounds__(512, 8) void k_knn(const unsigned short* __restrict__ xth,
                                                const unsigned short* __restrict__ xtl,
                                                const float* __restrict__ xt32,
                                                const float* __restrict__ sq,
                                                int* __restrict__ knn) {
  __shared__ unsigned short BjH[4096];   // 8 KB, frag-linear
  __shared__ unsigned short BjL[4096];   // 8 KB
  __shared__ float dt[32][68];           // 8.7 KB
  __shared__ float sqi_s[32], sqj_s[64];

  int it = blockIdx.x, b = blockIdx.y;
  int ibase = it * 32, tid = threadIdx.x;
  int lane = tid & 63, w = tid >> 6;     // 8 waves
  int tr = w >> 2, tc = w & 3;           // wave's MFMA tile (2x4 grid)

  const unsigned short* xhB = xth + (size_t)b * (NN / 16) * 1024;
  const unsigned short* xlB = xtl + (size_t)b * (NN / 16) * 1024;

  // A fragments for this wave's 16 rows, in regs
  size_t pa = ((size_t)(ibase >> 4) + tr) * 1024;
  bf16x8 ah0 = *(const bf16x8*)(xhB + pa +       lane * 8);
  bf16x8 ah1 = *(const bf16x8*)(xhB + pa + 512 + lane * 8);
  bf16x8 al0 = *(const bf16x8*)(xlB + pa +       lane * 8);
  bf16x8 al1 = *(const bf16x8*)(xlB + pa + 512 + lane * 8);

  if (tid < 32) sqi_s[tid] = sq[b * NN + ibase + tid];

  float ed[4]; int ei[4];
#pragma unroll
  for (int r = 0; r < 4; ++r) { ed[r] = 3.4e38f; ei[r] = -1; }

  // stage tile 0 (512 threads x 16B covers both 8KB buffers)
  gll16(xhB + tid * 8, BjH + tid * 8);
  gll16(xlB + tid * 8, BjL + tid * 8);
  if (tid < 64) sqj_s[tid] = sq[b * NN + tid];

  for (int jt = 0; jt < NN / 64; ++jt) {
    __syncthreads();                       // staged tile + sqj ready
    // ---- MFMA: one 16x16 tile per wave, K=64 via 2 chunks x 3 hi/lo terms
    {
      bf16x8 bh0 = *(const bf16x8*)(BjH + (tc * 2 + 0) * 512 + lane * 8);
      bf16x8 bh1 = *(const bf16x8*)(BjH + (tc * 2 + 1) * 512 + lane * 8);
      bf16x8 bl0 = *(const bf16x8*)(BjL + (tc * 2 + 0) * 512 + lane * 8);
      bf16x8 bl1 = *(const bf16x8*)(BjL + (tc * 2 + 1) * 512 + lane * 8);
      f32x4 acc = {0.f, 0.f, 0.f, 0.f};
      acc = __builtin_amdgcn_mfma_f32_16x16x32_bf16(ah0, bh0, acc, 0, 0, 0);
      acc = __builtin_amdgcn_mfma_f32_16x16x32_bf16(ah1, bh1, acc, 0, 0, 0);
      acc = __builtin_amdgcn_mfma_f32_16x16x32_bf16(ah0, bl0, acc, 0, 0, 0);
      acc = __builtin_amdgcn_mfma_f32_16x16x32_bf16(ah1, bl1, acc, 0, 0, 0);
      acc = __builtin_amdgcn_mfma_f32_16x16x32_bf16(al0, bh0, acc, 0, 0, 0);
      acc = __builtin_amdgcn_mfma_f32_16x16x32_bf16(al1, bh1, acc, 0, 0, 0);
      int jl = tc * 16 + (lane & 15);
      float sj = sqj_s[jl];
#pragma unroll
      for (int e = 0; e < 4; ++e) {
        int il = tr * 16 + (lane >> 4) * 4 + e;
        dt[il][jl] = sqi_s[il] + sj - 2.f * acc[e];
      }
    }
    __syncthreads();                       // dt ready, Bj free for overwrite
    int jbase = jt * 64;
    if (jt + 1 < NN / 64) {                // prefetch next tile under selection
      const unsigned short* sh = xhB + (size_t)(jt + 1) * 4096;
      const unsigned short* sl = xlB + (size_t)(jt + 1) * 4096;
      gll16(sh + tid * 8, BjH + tid * 8);
      gll16(sl + tid * 8, BjL + tid * 8);
      if (tid < 64) sqj_s[tid] = sq[b * NN + (jt + 1) * 64 + tid];
    }
    // ---- selection: wave w owns rows 4w..4w+3
    if (jt == 0) {
#pragma unroll
      for (int r = 0; r < 4; ++r) {
        int row = w * 4 + r, iglob = ibase + row;
        float d = dt[row][lane]; int j = lane;
        if (j == iglob) d = 3.4e38f;
#pragma unroll
        for (int size = 2; size <= 64; size <<= 1) {
#pragma unroll
          for (int stride = size >> 1; stride; stride >>= 1) {
            float od = __shfl_xor(d, stride);
            int   oj = __shfl_xor(j, stride);
            bool up = (lane & size) == 0;
            bool lower = (lane & stride) == 0;
            bool lt = (od < d) || (od == d && oj < j);
            bool take = (lower == up) ? lt : !lt;
            if (take) { d = od; j = oj; }
          }
        }
        if (lane < K2) { ed[r] = d; ei[r] = j; }
      }
    } else {
#pragma unroll
      for (int r = 0; r < 4; ++r) {
        int row = w * 4 + r, iglob = ibase + row;
        float thr = __shfl(ed[r], K2 - 1);
        float d = dt[row][lane]; int j = jbase + lane;
        u64 m = __ballot(d < thr && j != iglob);
        while (m) {
          int src = __ffsll(m) - 1;
          m &= m - 1;
          float dl = __shfl(d, src);
          int   jl = __shfl(j, src);
          u64 less = __ballot(ed[r] <= dl);
          int pos = __popcll(less);
          if (pos < K2) {
            float sd = __shfl_up(ed[r], 1);
            int   si = __shfl_up(ei[r], 1);
            if (lane >= pos && lane < K2) {
              ed[r] = (lane == pos) ? dl : sd;
              ei[r] = (lane == pos) ? jl : si;
            }
            thr = __shfl(ed[r], K2 - 1);   // refreshed 24th-best
            m &= __ballot(d < thr);        // prune stale candidates
          }
        }
      }
    }
  }

  // ---- exact fp64 refine of the K2 candidates, emit top-20
  const float* x32B = xt32 + (size_t)b * NN * FIN;
#pragma unroll
  for (int r = 0; r < 4; ++r) {
    int row = w * 4 + r, iglob = ibase + row;
    int j = (lane < K2) ? ei[r] : -1;
    double dd = 1e300;
    if (j >= 0) {
      const float4* xi4 = (const float4*)(x32B + (size_t)iglob * FIN);
      const float4* xj4 = (const float4*)(x32B + (size_t)j * FIN);
      double s = 0.0;
#pragma unroll
      for (int q = 0; q < 16; ++q) {
        float4 a = xi4[q], c = xj4[q];
        double d0 = (double)a.x - (double)c.x;
        double d1 = (double)a.y - (double)c.y;
        double d2 = (double)a.z - (double)c.z;
        double d3 = (double)a.w - (double)c.w;
        s += d0 * d0 + d1 * d1 + d2 * d2 + d3 * d3;
      }
      dd = s;
    }
#pragma unroll
    for (int size = 2; size <= 64; size <<= 1) {
#pragma unroll
      for (int stride = size >> 1; stride; stride >>= 1) {
        double od = __shfl_xor(dd, stride);
        int    oj = __shfl_xor(j, stride);
        bool up = (lane & size) == 0;
        bool lower = (lane & stride) == 0;
        bool lt = (od < dd) || (od == dd && oj < j);
        bool take = (lower == up) ? lt : !lt;
        if (take) { dd = od; j = oj; }
      }
    }
    if (lane < KK) knn[((size_t)b * NN + iglob) * KK + lane] = j;
  }
}

// ---------------------------------------------------------------- stats
__global__ __launch_bounds__(256) void k_stats(const float* __restrict__ P,
                                               const float* __restrict__ Q,
                                               const int* __restrict__ knn,
                                               float* __restrict__ mx,
                                               float* __restrict__ mn,
                                               double* __restrict__ sums) {
  __shared__ float Qs[2][NN];
  __shared__ int   ks[256][21];
  int nt = blockIdx.x, og = blockIdx.y, b = blockIdx.z;
  int tid = threadIdx.x;
  int nbase = nt * 256;
  for (int i = tid; i < 2 * NN; i += 256) {
    int ol = i >> 11, jj = i & (NN - 1);
    Qs[ol][jj] = Q[((size_t)b * FOUT + og * 2 + ol) * NN + jj];
  }
  for (int i = tid; i < 256 * KK; i += 256) {
    int nn = i / KK, k = i % KK;
    ks[nn][k] = knn[((size_t)b * NN + nbase + nn) * KK + k];
  }
  __syncthreads();
  int ol = tid >> 7, ln = tid & 127;
  int o = og * 2 + ol;
  float s1 = 0.f, s2 = 0.f;
#pragma unroll
  for (int s = 0; s < 2; ++s) {
    int nn = ln + 128 * s;
    int n = nbase + nn;
    float p = P[((size_t)b * FOUT + o) * NN + n];
    float vmx = -3.4e38f, vmn = 3.4e38f;
#pragma unroll
    for (int k = 0; k < KK; ++k) {
      float y = p + Qs[ol][ks[nn][k]];
      s1 += y; s2 += y * y;
      vmx = fmaxf(vmx, y); vmn = fminf(vmn, y);
    }
    mx[((size_t)b * FOUT + o) * NN + n] = vmx;
    mn[((size_t)b * FOUT + o) * NN + n] = vmn;
  }
#pragma unroll
  for (int off = 32; off; off >>= 1) { s1 += __shfl_xor(s1, off); s2 += __shfl_xor(s2, off); }
  if ((tid & 63) == 0) {
    atomicAdd(&sums[o], (double)s1);
    atomicAdd(&sums[FOUT + o], (double)s2);
  }
}

// ---------------------------------------------------------------- finalize
__global__ void k_finalize(const double* __restrict__ sums, const float* __restrict__ gamma,
                           const float* __restrict__ beta, float* __restrict__ ss) {
  int o = threadIdx.x;
  if (o < FOUT) {
    double cnt = (double)Bb * NN * KK;
    double mean = sums[o] / cnt;
    double var = sums[FOUT + o] / cnt - mean * mean;
    double inv = 1.0 / sqrt(var + 1e-5);
    double scale = (double)gamma[o] * inv;
    ss[o] = (float)scale;
    ss[FOUT + o] = (float)((double)beta[o] - mean * scale);
  }
}

// ---------------------------------------------------------------- epilogue
__global__ __launch_bounds__(256) void k_out(const float* __restrict__ mx,
                                             const float* __restrict__ mn,
                                             const float* __restrict__ ss,
                                             float* __restrict__ out) {
  int idx = blockIdx.x * 256 + threadIdx.x;
  int o = (idx >> 11) & (FOUT - 1);
  float sc = ss[o], sh = ss[FOUT + o];
  float v = (sc >= 0.f) ? mx[idx] : mn[idx];
  out[idx] = fmaxf(sc * v + sh, 0.f);
}

// ---------------------------------------------------------------- launch
extern "C" void kernel_launch(void* const* d_in, const int* in_sizes, int n_in,
                              void* d_out, int out_size, void* d_ws, size_t ws_size,
                              hipStream_t stream) {
  const float* x     = (const float*)d_in[0];
  const float* W     = (const float*)d_in[1];
  const float* bias  = (const float*)d_in[2];
  const float* gamma = (const float*)d_in[3];
  const float* beta  = (const float*)d_in[4];
  float* out = (float*)d_out;

  char* ws = (char*)d_ws;
  const size_t PN = (size_t)Bb * FOUT * NN;          // 4,194,304
  float* P  = (float*)ws;  ws += PN * 4;
  float* Q  = (float*)ws;  ws += PN * 4;
  float* mx = (float*)ws;  ws += PN * 4;             // 16 MB, aliased with xt*
  float* mn = (float*)ws;  ws += PN * 4;
  float* sq = (float*)ws;  ws += (size_t)Bb * NN * 4;
  int*   knn = (int*)ws;   ws += (size_t)Bb * NN * KK * 4;
  double* sums = (double*)ws; ws += 2 * FOUT * 8;
  float* ss = (float*)ws;  ws += 2 * FOUT * 4;

  // xth/xtl/xt32 alias the mx buffer (4+4+8 MB = 16 MB); k_stats overwrites
  // mx only after k_knn has finished reading them (stream-ordered).
  unsigned short* xth = (unsigned short*)mx;
  unsigned short* xtl = xth + (size_t)Bb * NN * FIN;
  float* xt32 = (float*)(xtl + (size_t)Bb * NN * FIN);

  hipMemsetAsync(sums, 0, 2 * FOUT * 8, stream);

  k_prep<<<dim3(NN / 64, Bb), 256, 0, stream>>>(x, xth, xtl, xt32, sq);
  k_pq<<<dim3(32, 4, Bb), 256, 0, stream>>>(x, W, bias, P, Q);
  k_knn<<<dim3(NN / 32, Bb), 512, 0, stream>>>(xth, xtl, xt32, sq, knn);
  k_stats<<<dim3(8, 64, Bb), 256, 0, stream>>>(P, Q, knn, mx, mn, sums);
  k_finalize<<<1, 128, 0, stream>>>(sums, gamma, beta, ss);
  k_out<<<(int)(PN / 256), 256, 0, stream>>>(mx, mn, ss, out);
}

// Round 4
// 508.588 us; speedup vs baseline: 2.3102x; 1.0575x over previous
//
#include <hip/hip_runtime.h>
#include <hip/hip_bf16.h>

#define Bb   16
#define FIN  64
#define FOUT 128
#define NN   2048
#define KK   20
#define K2   24   // capture top-24 (approx), refine to top-20 (exact fp64)

typedef unsigned long long u64;
typedef __attribute__((ext_vector_type(8))) __bf16 bf16x8;
typedef __attribute__((ext_vector_type(4))) float  f32x4;

static __device__ __forceinline__ unsigned short f2bf(float f) {
  unsigned u = __float_as_uint(f);
  unsigned r = (u + 0x7fff + ((u >> 16) & 1)) >> 16;   // RNE
  return (unsigned short)r;
}
static __device__ __forceinline__ float bf2f(unsigned short b) {
  return __uint_as_float(((unsigned)b) << 16);
}
static __device__ __forceinline__ void gll16(const void* g, void* l) {
  __builtin_amdgcn_global_load_lds(
      (const __attribute__((address_space(1))) unsigned int*)g,
      (__attribute__((address_space(3))) unsigned int*)l, 16, 0, 0);
}

// ---------------------------------------------------------------- prep:
// transpose x -> xt32[b][n][f] (fp32), bf16 hi/lo split packed in MFMA
// fragment order. Also sq[b][n].
__global__ __launch_bounds__(256) void k_prep(const float* __restrict__ x,
                                              unsigned short* __restrict__ xth,
                                              unsigned short* __restrict__ xtl,
                                              float* __restrict__ xt32,
                                              float* __restrict__ sq) {
  __shared__ float ts[FIN][65];
  int nt = blockIdx.x, b = blockIdx.y;
  int nbase = nt * 64, tid = threadIdx.x;
  for (int i = tid; i < 64 * 64; i += 256) {
    int f = i >> 6, j = i & 63;
    ts[f][j] = x[((size_t)b * FIN + f) * NN + nbase + j];
  }
  __syncthreads();
  if (tid < 64) {
    float s = 0.f;
#pragma unroll
    for (int f = 0; f < FIN; ++f) { float v = ts[f][tid]; s += v * v; }
    sq[b * NN + nbase + tid] = s;
  }
  for (int u = tid; u < 512; u += 256) {
    int lane = u & 63, ck = (u >> 6) & 1, pg = u >> 7;
    int j = pg * 16 + (lane & 15);
    int kg = lane >> 4;
    int fbase = ck * 32 + kg * 8;
    float v[8]; unsigned short h[8], l[8];
#pragma unroll
    for (int e = 0; e < 8; ++e) {
      v[e] = ts[fbase + e][j];
      h[e] = f2bf(v[e]);
      l[e] = f2bf(v[e] - bf2f(h[e]));
    }
    size_t po = (((size_t)b * (NN / 16) + (nbase >> 4) + pg) * 2 + ck) * 512 + lane * 8;
    ushort4* dh = (ushort4*)(xth + po);
    dh[0] = make_ushort4(h[0], h[1], h[2], h[3]);
    dh[1] = make_ushort4(h[4], h[5], h[6], h[7]);
    ushort4* dl = (ushort4*)(xtl + po);
    dl[0] = make_ushort4(l[0], l[1], l[2], l[3]);
    dl[1] = make_ushort4(l[4], l[5], l[6], l[7]);
    float* d32 = xt32 + ((size_t)b * NN + nbase + j) * FIN + fbase;
    *(float4*)d32       = make_float4(v[0], v[1], v[2], v[3]);
    *(float4*)(d32 + 4) = make_float4(v[4], v[5], v[6], v[7]);
  }
}

// ---------------------------------------------------------------- P/Q GEMM
// Emits TRANSPOSED Pt[b][n][o] (o in [0,128), bias added) and Qt[b][n][o].
__global__ __launch_bounds__(256) void k_pq(const float* __restrict__ x,
                                            const float* __restrict__ W,
                                            const float* __restrict__ bias,
                                            float* __restrict__ Pt,
                                            float* __restrict__ Qt) {
  __shared__ float Ws[64][68];
  __shared__ float xs[64][68];
  __shared__ float ts[64][65];
  int L = blockIdx.x;
  int bl = L & 7, nt = (L >> 3) & 31, ot = (L >> 8) & 3, bh = L >> 10;
  int b = bl | (bh << 3);
  int tid = threadIdx.x;
  for (int i = tid; i < 64 * 64; i += 256) {
    int f = i & 63, r = i >> 6;
    int R = ot * 64 + r;
    float w;
    if (R < FOUT) w = W[R * 2 * FIN + f] - W[R * 2 * FIN + FIN + f];
    else          w = W[(R - FOUT) * 2 * FIN + FIN + f];
    Ws[r][f] = w;
  }
  const float* xb = x + (size_t)b * FIN * NN + nt * 64;
  for (int i = tid; i < 64 * 64; i += 256) {
    int nn = i & 63, f = i >> 6;
    xs[nn][f] = xb[(size_t)f * NN + nn];
  }
  __syncthreads();
  int tx = tid & 15, ty = tid >> 4;
  int r0 = ty * 4;
  float acc[4][4] = {};
#pragma unroll
  for (int f = 0; f < 64; f += 4) {
    float4 a[4], c[4];
#pragma unroll
    for (int i = 0; i < 4; ++i) a[i] = *(const float4*)&Ws[r0 + i][f];
#pragma unroll
    for (int j = 0; j < 4; ++j) c[j] = *(const float4*)&xs[tx + 16 * j][f];
#pragma unroll
    for (int i = 0; i < 4; ++i)
#pragma unroll
      for (int j = 0; j < 4; ++j)
        acc[i][j] += a[i].x * c[j].x + a[i].y * c[j].y + a[i].z * c[j].z + a[i].w * c[j].w;
  }
#pragma unroll
  for (int i = 0; i < 4; ++i) {
    int R = ot * 64 + r0 + i;
    float add = (R < FOUT) ? bias[R] : 0.f;
#pragma unroll
    for (int j = 0; j < 4; ++j)
      ts[tx + 16 * j][r0 + i] = acc[i][j] + add;
  }
  __syncthreads();
  float* dst = (ot < 2) ? Pt : Qt;
  int obase = (ot & 1) * 64;
  for (int i = tid; i < 4096; i += 256) {
    int n_l = i >> 6, o_l = i & 63;
    dst[((size_t)b * NN + nt * 64 + n_l) * FOUT + obase + o_l] = ts[n_l][o_l];
  }
}

// ---------------------------------------------------------------- kNN
// 32-row blocks, 8 waves. XCD-swizzled 1D grid: b in low 3 bits -> each
// XCD's resident blocks share <=2 b values (working set ~2MB < 4MB L2).
__global__ __launch_bounds__(512, 8) void k_knn(const unsigned short* __restrict__ xth,
                                                const unsigned short* __restrict__ xtl,
                                                const float* __restrict__ xt32,
                                                const float* __restrict__ sq,
                                                int* __restrict__ knn) {
  __shared__ unsigned short BjH[4096];   // 8 KB, frag-linear
  __shared__ unsigned short BjL[4096];   // 8 KB
  __shared__ float dt[32][68];           // 8.7 KB
  __shared__ float sqi_s[32], sqj_s[64];

  int L = blockIdx.x;
  int b = (L & 7) | ((L >> 9) << 3);
  int it = (L >> 3) & 63;
  int ibase = it * 32, tid = threadIdx.x;
  int lane = tid & 63, w = tid >> 6;     // 8 waves
  int tr = w >> 2, tc = w & 3;           // wave's MFMA tile (2x4 grid)

  const unsigned short* xhB = xth + (size_t)b * (NN / 16) * 1024;
  const unsigned short* xlB = xtl + (size_t)b * (NN / 16) * 1024;

  size_t pa = ((size_t)(ibase >> 4) + tr) * 1024;
  bf16x8 ah0 = *(const bf16x8*)(xhB + pa +       lane * 8);
  bf16x8 ah1 = *(const bf16x8*)(xhB + pa + 512 + lane * 8);
  bf16x8 al0 = *(const bf16x8*)(xlB + pa +       lane * 8);
  bf16x8 al1 = *(const bf16x8*)(xlB + pa + 512 + lane * 8);

  if (tid < 32) sqi_s[tid] = sq[b * NN + ibase + tid];

  float ed[4]; int ei[4];
#pragma unroll
  for (int r = 0; r < 4; ++r) { ed[r] = 3.4e38f; ei[r] = -1; }

  gll16(xhB + tid * 8, BjH + tid * 8);
  gll16(xlB + tid * 8, BjL + tid * 8);
  if (tid < 64) sqj_s[tid] = sq[b * NN + tid];

  for (int jt = 0; jt < NN / 64; ++jt) {
    __syncthreads();
    {
      bf16x8 bh0 = *(const bf16x8*)(BjH + (tc * 2 + 0) * 512 + lane * 8);
      bf16x8 bh1 = *(const bf16x8*)(BjH + (tc * 2 + 1) * 512 + lane * 8);
      bf16x8 bl0 = *(const bf16x8*)(BjL + (tc * 2 + 0) * 512 + lane * 8);
      bf16x8 bl1 = *(const bf16x8*)(BjL + (tc * 2 + 1) * 512 + lane * 8);
      f32x4 acc = {0.f, 0.f, 0.f, 0.f};
      acc = __builtin_amdgcn_mfma_f32_16x16x32_bf16(ah0, bh0, acc, 0, 0, 0);
      acc = __builtin_amdgcn_mfma_f32_16x16x32_bf16(ah1, bh1, acc, 0, 0, 0);
      acc = __builtin_amdgcn_mfma_f32_16x16x32_bf16(ah0, bl0, acc, 0, 0, 0);
      acc = __builtin_amdgcn_mfma_f32_16x16x32_bf16(ah1, bl1, acc, 0, 0, 0);
      acc = __builtin_amdgcn_mfma_f32_16x16x32_bf16(al0, bh0, acc, 0, 0, 0);
      acc = __builtin_amdgcn_mfma_f32_16x16x32_bf16(al1, bh1, acc, 0, 0, 0);
      int jl = tc * 16 + (lane & 15);
      float sj = sqj_s[jl];
#pragma unroll
      for (int e = 0; e < 4; ++e) {
        int il = tr * 16 + (lane >> 4) * 4 + e;
        dt[il][jl] = sqi_s[il] + sj - 2.f * acc[e];
      }
    }
    __syncthreads();
    int jbase = jt * 64;
    if (jt + 1 < NN / 64) {
      const unsigned short* sh = xhB + (size_t)(jt + 1) * 4096;
      const unsigned short* sl = xlB + (size_t)(jt + 1) * 4096;
      gll16(sh + tid * 8, BjH + tid * 8);
      gll16(sl + tid * 8, BjL + tid * 8);
      if (tid < 64) sqj_s[tid] = sq[b * NN + (jt + 1) * 64 + tid];
    }
    if (jt == 0) {
#pragma unroll
      for (int r = 0; r < 4; ++r) {
        int row = w * 4 + r, iglob = ibase + row;
        float d = dt[row][lane]; int j = lane;
        if (j == iglob) d = 3.4e38f;
#pragma unroll
        for (int size = 2; size <= 64; size <<= 1) {
#pragma unroll
          for (int stride = size >> 1; stride; stride >>= 1) {
            float od = __shfl_xor(d, stride);
            int   oj = __shfl_xor(j, stride);
            bool up = (lane & size) == 0;
            bool lower = (lane & stride) == 0;
            bool lt = (od < d) || (od == d && oj < j);
            bool take = (lower == up) ? lt : !lt;
            if (take) { d = od; j = oj; }
          }
        }
        if (lane < K2) { ed[r] = d; ei[r] = j; }
      }
    } else {
#pragma unroll
      for (int r = 0; r < 4; ++r) {
        int row = w * 4 + r, iglob = ibase + row;
        float thr = __shfl(ed[r], K2 - 1);
        float d = dt[row][lane]; int j = jbase + lane;
        u64 m = __ballot(d < thr && j != iglob);
        while (m) {
          int src = __ffsll(m) - 1;
          m &= m - 1;
          float dl = __shfl(d, src);
          int   jl = __shfl(j, src);
          u64 less = __ballot(ed[r] <= dl);
          int pos = __popcll(less);
          if (pos < K2) {
            float sd = __shfl_up(ed[r], 1);
            int   si = __shfl_up(ei[r], 1);
            if (lane >= pos && lane < K2) {
              ed[r] = (lane == pos) ? dl : sd;
              ei[r] = (lane == pos) ? jl : si;
            }
            thr = __shfl(ed[r], K2 - 1);
            m &= __ballot(d < thr);
          }
        }
      }
    }
  }

  const float* x32B = xt32 + (size_t)b * NN * FIN;
#pragma unroll
  for (int r = 0; r < 4; ++r) {
    int row = w * 4 + r, iglob = ibase + row;
    int j = (lane < K2) ? ei[r] : -1;
    double dd = 1e300;
    if (j >= 0) {
      const float4* xi4 = (const float4*)(x32B + (size_t)iglob * FIN);
      const float4* xj4 = (const float4*)(x32B + (size_t)j * FIN);
      double s = 0.0;
#pragma unroll
      for (int q = 0; q < 16; ++q) {
        float4 a = xi4[q], c = xj4[q];
        double d0 = (double)a.x - (double)c.x;
        double d1 = (double)a.y - (double)c.y;
        double d2 = (double)a.z - (double)c.z;
        double d3 = (double)a.w - (double)c.w;
        s += d0 * d0 + d1 * d1 + d2 * d2 + d3 * d3;
      }
      dd = s;
    }
#pragma unroll
    for (int size = 2; size <= 64; size <<= 1) {
#pragma unroll
      for (int stride = size >> 1; stride; stride >>= 1) {
        double od = __shfl_xor(dd, stride);
        int    oj = __shfl_xor(j, stride);
        bool up = (lane & size) == 0;
        bool lower = (lane & stride) == 0;
        bool lt = (od < dd) || (od == dd && oj < j);
        bool take = (lower == up) ? lt : !lt;
        if (take) { dd = od; j = oj; }
      }
    }
    if (lane < KK) knn[((size_t)b * NN + iglob) * KK + lane] = j;
  }
}

// ---------------------------------------------------------------- stats
// Transposed gather: per (b, 128-n chunk), threads own one o each (x4 n-groups).
// Every Qt gather is a coalesced 512B o-row; knn read exactly once.
__global__ __launch_bounds__(512) void k_stats(const float* __restrict__ Pt,
                                               const float* __restrict__ Qt,
                                               const int* __restrict__ knn,
                                               float* __restrict__ mxT,
                                               float* __restrict__ mnT,
                                               double* __restrict__ sums) {
  __shared__ int ks[128 * KK];          // 10 KB
  __shared__ float rs[2][4][FOUT];      // 4 KB
  int L = blockIdx.x;
  int b = (L & 7) | ((L >> 7) << 3);
  int nt = (L >> 3) & 15;
  int tid = threadIdx.x;
  int o = tid & 127, ng = tid >> 7;     // 4 n-groups
  int nbase = nt * 128;
  for (int i = tid; i < 128 * KK; i += 512)
    ks[i] = knn[((size_t)b * NN + nbase + i / KK) * KK + i % KK];
  __syncthreads();
  const float* PtB = Pt + (size_t)b * NN * FOUT + o;
  const float* QtB = Qt + (size_t)b * NN * FOUT + o;
  float s1 = 0.f, s2 = 0.f;
  for (int nl = ng * 32; nl < ng * 32 + 32; ++nl) {
    int n = nbase + nl;
    float p = PtB[(size_t)n * FOUT];
    float vmx = -3.4e38f, vmn = 3.4e38f;
#pragma unroll
    for (int k = 0; k < KK; ++k) {
      float q = QtB[(size_t)ks[nl * KK + k] * FOUT];
      float y = p + q;
      s1 += y; s2 = fmaf(y, y, s2);
      vmx = fmaxf(vmx, y); vmn = fminf(vmn, y);
    }
    mxT[((size_t)b * NN + n) * FOUT + o] = vmx;
    mnT[((size_t)b * NN + n) * FOUT + o] = vmn;
  }
  rs[0][ng][o] = s1; rs[1][ng][o] = s2;
  __syncthreads();
  if (tid < FOUT) {
    float a = rs[0][0][tid] + rs[0][1][tid] + rs[0][2][tid] + rs[0][3][tid];
    float c = rs[1][0][tid] + rs[1][1][tid] + rs[1][2][tid] + rs[1][3][tid];
    atomicAdd(&sums[tid], (double)a);
    atomicAdd(&sums[FOUT + tid], (double)c);
  }
}

// ---------------------------------------------------------------- finalize
__global__ void k_finalize(const double* __restrict__ sums, const float* __restrict__ gamma,
                           const float* __restrict__ beta, float* __restrict__ ss) {
  int o = threadIdx.x;
  if (o < FOUT) {
    double cnt = (double)Bb * NN * KK;
    double mean = sums[o] / cnt;
    double var = sums[FOUT + o] / cnt - mean * mean;
    double inv = 1.0 / sqrt(var + 1e-5);
    double scale = (double)gamma[o] * inv;
    ss[o] = (float)scale;
    ss[FOUT + o] = (float)((double)beta[o] - mean * scale);
  }
}

// ---------------------------------------------------------------- epilogue
// Reads the needed extremum (by sign of scale) from [b][n][o], LDS-transposes,
// writes out[b][o][n] coalesced.
__global__ __launch_bounds__(256) void k_out(const float* __restrict__ mxT,
                                             const float* __restrict__ mnT,
                                             const float* __restrict__ ss,
                                             float* __restrict__ out) {
  __shared__ float ts[64][65];
  int L = blockIdx.x;
  int b = (L & 7) | ((L >> 9) << 3);
  int nt = (L >> 3) & 31, ot = (L >> 8) & 1;
  int tid = threadIdx.x;
  int nbase = nt * 64, obase = ot * 64;
  for (int i = tid; i < 4096; i += 256) {
    int o_l = i & 63, n_l = i >> 6;
    int o = obase + o_l;
    float sc = ss[o];
    const float* src = (sc >= 0.f) ? mxT : mnT;
    ts[o_l][n_l] = src[((size_t)b * NN + nbase + n_l) * FOUT + o];
  }
  __syncthreads();
  for (int i = tid; i < 4096; i += 256) {
    int n_l = i & 63, o_l = i >> 6;
    int o = obase + o_l;
    float sc = ss[o], sh = ss[FOUT + o];
    out[((size_t)b * FOUT + o) * NN + nbase + n_l] = fmaxf(fmaf(sc, ts[o_l][n_l], sh), 0.f);
  }
}

// ---------------------------------------------------------------- launch
extern "C" void kernel_launch(void* const* d_in, const int* in_sizes, int n_in,
                              void* d_out, int out_size, void* d_ws, size_t ws_size,
                              hipStream_t stream) {
  const float* x     = (const float*)d_in[0];
  const float* W     = (const float*)d_in[1];
  const float* bias  = (const float*)d_in[2];
  const float* gamma = (const float*)d_in[3];
  const float* beta  = (const float*)d_in[4];
  float* out = (float*)d_out;

  char* ws = (char*)d_ws;
  const size_t PN = (size_t)Bb * FOUT * NN;          // 4,194,304
  float* Pt = (float*)ws;  ws += PN * 4;
  float* Qt = (float*)ws;  ws += PN * 4;
  float* mxT = (float*)ws; ws += PN * 4;             // 16 MB, aliased with xt*
  float* mnT = (float*)ws; ws += PN * 4;
  float* sq = (float*)ws;  ws += (size_t)Bb * NN * 4;
  int*   knn = (int*)ws;   ws += (size_t)Bb * NN * KK * 4;
  double* sums = (double*)ws; ws += 2 * FOUT * 8;
  float* ss = (float*)ws;  ws += 2 * FOUT * 4;

  // xth/xtl/xt32 alias the mxT buffer (4+4+8 MB = 16 MB); k_stats overwrites
  // mxT only after k_knn has finished reading them (stream-ordered).
  unsigned short* xth = (unsigned short*)mxT;
  unsigned short* xtl = xth + (size_t)Bb * NN * FIN;
  float* xt32 = (float*)(xtl + (size_t)Bb * NN * FIN);

  hipMemsetAsync(sums, 0, 2 * FOUT * 8, stream);

  k_prep<<<dim3(NN / 64, Bb), 256, 0, stream>>>(x, xth, xtl, xt32, sq);
  k_pq<<<2048, 256, 0, stream>>>(x, W, bias, Pt, Qt);
  k_knn<<<1024, 512, 0, stream>>>(xth, xtl, xt32, sq, knn);
  k_stats<<<256, 512, 0, stream>>>(Pt, Qt, knn, mxT, mnT, sums);
  k_finalize<<<1, 128, 0, stream>>>(sums, gamma, beta, ss);
  k_out<<<1024, 256, 0, stream>>>(mxT, mnT, ss, out);
}